// Round 13
// baseline (132.658 us; speedup 1.0000x reference)
//
#include <hip/hip_runtime.h>
#include <cstdio>

// ---------------------------------------------------------------------------
// TransformerLayer (B=8, C=128, N=4096) — round 13:
//   Attention with 64-i waves, NO persistent Q register file (r10/r11 spilled
//   on qa[2][8]): q stored by qkv in a swizzled layout
//   [(n>>5)][c>>3][n&31][c&7] so each (ib,ck) Q-fragment is one coalesced
//   1KB wave b128 load from L2. Per-ck loads inside unroll-2 QK loop cap
//   register pressure (~210 < 256). Geometry = r10: 512 blk (8b x 16 it x
//   4 sp), 256 thr, 64KB LDS dbuf, 2 blocks/CU; LDS reads/CU halve vs r9.
//   k1: fused qkv MFMA (r12) with q-epilogue writing the swizzled layout.
//   k3: final proj MFMA (r12) extended to 4 bf16 pO planes.
// ws: qt 8 | kt 8 | v 8 | pO(bf16) 32 | lw 0.5 MB  (56.5 MB)
// ---------------------------------------------------------------------------

#define BATCH 8
#define CH    128
#define NPOS  4096
#define BCN   (BATCH * CH * NPOS)
#define LOG2E 1.4426950408889634f

typedef __attribute__((ext_vector_type(8)))  short bf16x8;
typedef __attribute__((ext_vector_type(16))) float f32x16;
typedef unsigned short ushort_t;
typedef unsigned int   uint32;

#if __has_builtin(__builtin_amdgcn_exp2f)
#define EXP2(x) __builtin_amdgcn_exp2f(x)
#else
#define EXP2(x) exp2f(x)
#endif

__device__ inline ushort_t f2bf(float f) {
    uint32 u = __float_as_uint(f);
    u += 0x7FFFu + ((u >> 16) & 1u);
    return (ushort_t)(u >> 16);
}
__device__ inline float bf2f(ushort_t h) {
    return __uint_as_float(((uint32)h) << 16);
}
__device__ inline f32x16 z16() {
    f32x16 r;
#pragma unroll
    for (int i = 0; i < 16; ++i) r[i] = 0.f;
    return r;
}
// async global->LDS, 16B/lane; LDS dst must be wave-uniform base
__device__ inline void gl_lds16(const ushort_t* g, ushort_t* l) {
    __builtin_amdgcn_global_load_lds(
        (const __attribute__((address_space(1))) uint32*)g,
        (__attribute__((address_space(3))) uint32*)l, 16, 0, 0);
}
// 8 fp32 -> bf16x8 (scaled), via v_cvt_pk_bf16_f32
__device__ inline bf16x8 cvt8(const float* p, float s) {
    const float4 a = *(const float4*)p;
    const float4 c = *(const float4*)(p + 4);
    uint32 u0, u1, u2, u3;
    asm("v_cvt_pk_bf16_f32 %0, %1, %2" : "=v"(u0) : "v"(a.x * s), "v"(a.y * s));
    asm("v_cvt_pk_bf16_f32 %0, %1, %2" : "=v"(u1) : "v"(a.z * s), "v"(a.w * s));
    asm("v_cvt_pk_bf16_f32 %0, %1, %2" : "=v"(u2) : "v"(c.x * s), "v"(c.y * s));
    asm("v_cvt_pk_bf16_f32 %0, %1, %2" : "=v"(u3) : "v"(c.z * s), "v"(c.w * s));
    union { uint32 u[4]; bf16x8 v; } r;
    r.u[0] = u0; r.u[1] = u1; r.u[2] = u2; r.u[3] = u3;
    return r.v;
}
// (p0+p1+p2+p3)*s elementwise -> bf16x8
__device__ inline bf16x8 comb4(bf16x8 p0, bf16x8 p1, bf16x8 p2, bf16x8 p3, float s) {
    uint32 u[4];
#pragma unroll
    for (int i = 0; i < 4; ++i) {
        const float a = (bf2f((ushort_t)p0[2 * i]) + bf2f((ushort_t)p1[2 * i]) +
                         bf2f((ushort_t)p2[2 * i]) + bf2f((ushort_t)p3[2 * i])) * s;
        const float b = (bf2f((ushort_t)p0[2 * i + 1]) + bf2f((ushort_t)p1[2 * i + 1]) +
                         bf2f((ushort_t)p2[2 * i + 1]) + bf2f((ushort_t)p3[2 * i + 1])) * s;
        asm("v_cvt_pk_bf16_f32 %0, %1, %2" : "=v"(u[i]) : "v"(a), "v"(b));
    }
    union { uint32 uu[4]; bf16x8 v; } r;
    r.uu[0] = u[0]; r.uu[1] = u[1]; r.uu[2] = u[2]; r.uu[3] = u[3];
    return r.v;
}

// ------------------------------------------------- k1: fused qkv via MFMA
// grid 512 = 8 b x 64 n-tiles(64), 256 thr = 4 waves; wave w = co-block w.
// q epilogue writes the SWIZZLED layout:
//   off(n,c) = ((n>>5)*16 + (c>>3))*256 + (n&31)*8 + (c&7)   [ushorts]
// so attn's per-(ib,ck) Q-fragment = one coalesced wave b128 load.
__global__ __launch_bounds__(256, 2)
void qkv_mfma_kernel(const float* __restrict__ x,
                     const float* __restrict__ Wq, const float* __restrict__ bq,
                     const float* __restrict__ Wk, const float* __restrict__ bk,
                     const float* __restrict__ Wv, const float* __restrict__ bv_,
                     ushort_t* __restrict__ qt, ushort_t* __restrict__ kt,
                     ushort_t* __restrict__ vb)
{
    __shared__ float    xs[32][69];      // staging chunk
    __shared__ ushort_t xh[64][136];     // x hi bf16 [n][c]
    __shared__ ushort_t xl[64][136];     // x lo bf16 [n][c]

    const int blk = blockIdx.x;
    const int b   = blk & 7;             // batch == XCD
    const int n0  = (blk >> 3) * 64;

    const int tid = threadIdx.x;
    const int w   = tid >> 6;
    const int l   = tid & 63;
    const int l31 = l & 31;
    const int g2  = l >> 5;

    // ---- phase 1: stage + transpose + hi/lo convert (block-cooperative)
    for (int c0 = 0; c0 < CH; c0 += 32) {
        __syncthreads();
        {
            const int r = tid >> 3, f4 = tid & 7;
            const size_t base = (size_t)(b * CH + c0 + r) * NPOS + n0;
            *(float4*)&xs[r][4 * f4]      = *(const float4*)&x[base + 4 * f4];
            *(float4*)&xs[r][32 + 4 * f4] = *(const float4*)&x[base + 32 + 4 * f4];
        }
        __syncthreads();
        {
            const int n = tid >> 2, oc = tid & 3;
            bf16x8 hi, lo;
#pragma unroll
            for (int m = 0; m < 8; ++m) {
                const float v = xs[oc * 8 + m][n];
                const ushort_t h = f2bf(v);
                hi[m] = (short)h;
                lo[m] = (short)f2bf(v - bf2f(h));
            }
            *(bf16x8*)&xh[n][c0 + oc * 8] = hi;
            *(bf16x8*)&xl[n][c0 + oc * 8] = lo;
        }
    }
    __syncthreads();

    // ---- phase 2: MFMA k-loop
    f32x16 aq0 = z16(), aq1 = z16(), ak0 = z16(), ak1 = z16();
    f32x16 av0 = z16(), av1 = z16();
    const int co = w * 32 + l31;
    const size_t wrow = (size_t)co * CH;

#pragma unroll
    for (int k = 0; k < 8; ++k) {
        const int ko = k * 16 + g2 * 8;
        const bf16x8 xh0 = *(const bf16x8*)&xh[l31][ko];
        const bf16x8 xh1 = *(const bf16x8*)&xh[32 + l31][ko];
        const bf16x8 xl0 = *(const bf16x8*)&xl[l31][ko];
        const bf16x8 xl1 = *(const bf16x8*)&xl[32 + l31][ko];
        const bf16x8 wqf = cvt8(Wq + wrow + ko, 1.0f);
        const bf16x8 wkf = cvt8(Wk + wrow + ko, LOG2E);
        const bf16x8 wvf = cvt8(Wv + wrow + ko, 1.0f);

        aq0 = __builtin_amdgcn_mfma_f32_32x32x16_bf16(xh0, wqf, aq0, 0, 0, 0);
        aq0 = __builtin_amdgcn_mfma_f32_32x32x16_bf16(xl0, wqf, aq0, 0, 0, 0);
        aq1 = __builtin_amdgcn_mfma_f32_32x32x16_bf16(xh1, wqf, aq1, 0, 0, 0);
        aq1 = __builtin_amdgcn_mfma_f32_32x32x16_bf16(xl1, wqf, aq1, 0, 0, 0);
        ak0 = __builtin_amdgcn_mfma_f32_32x32x16_bf16(xh0, wkf, ak0, 0, 0, 0);
        ak0 = __builtin_amdgcn_mfma_f32_32x32x16_bf16(xl0, wkf, ak0, 0, 0, 0);
        ak1 = __builtin_amdgcn_mfma_f32_32x32x16_bf16(xh1, wkf, ak1, 0, 0, 0);
        ak1 = __builtin_amdgcn_mfma_f32_32x32x16_bf16(xl1, wkf, ak1, 0, 0, 0);
        av0 = __builtin_amdgcn_mfma_f32_32x32x16_bf16(wvf, xh0, av0, 0, 0, 0);
        av0 = __builtin_amdgcn_mfma_f32_32x32x16_bf16(wvf, xl0, av0, 0, 0, 0);
        av1 = __builtin_amdgcn_mfma_f32_32x32x16_bf16(wvf, xh1, av1, 0, 0, 0);
        av1 = __builtin_amdgcn_mfma_f32_32x32x16_bf16(wvf, xl1, av1, 0, 0, 0);
    }

    // ---- epilogue
    const float bqv = bq[co];
    const float bkv = bk[co] * LOG2E;
    ushort_t* qtb = qt + (size_t)b * NPOS * CH;   // swizzled layout
    ushort_t* ktb = kt + (size_t)b * NPOS * CH;
    ushort_t* vbb = vb + (size_t)b * CH * NPOS;

#pragma unroll
    for (int rg = 0; rg < 16; ++rg) {
        const int rr = (rg & 3) + 8 * (rg >> 2) + 4 * g2;
        {
            const int na  = n0 + rr;
            const int nb2 = n0 + 32 + rr;
            // q: swizzled store
            const uint32 offa = (uint32)(((na >> 5) * 16 + (co >> 3)) << 8) +
                                ((na & 31) << 3) + (co & 7);
            const uint32 offb = (uint32)(((nb2 >> 5) * 16 + (co >> 3)) << 8) +
                                ((nb2 & 31) << 3) + (co & 7);
            qtb[offa] = f2bf(aq0[rg] + bqv);
            qtb[offb] = f2bf(aq1[rg] + bqv);
            // k: row-major [n][c] (global_load_lds staging needs it)
            ktb[(size_t)na * CH + co]  = f2bf(ak0[rg] + bkv);
            ktb[(size_t)nb2 * CH + co] = f2bf(ak1[rg] + bkv);
        }
        {   // v: [co][n]
            const int cov = w * 32 + rr;
            const float bvv = bv_[cov];
            vbb[(size_t)cov * NPOS + n0 + l31]      = f2bf(av0[rg] + bvv);
            vbb[(size_t)cov * NPOS + n0 + 32 + l31] = f2bf(av1[rg] + bvv);
        }
    }
}

// ------------------------------------------------------- k2: MFMA attention
// 512 blocks x 256 thr (4 waves). blk -> b=blk&7 (XCD), it (16 tiles of 256 i),
// sp (j-quarter). Wave w owns 64 i-rows (2 i-blocks): each K/V LDS b128 feeds
// 2 MFMAs. Q-fragments loaded per-ck from the swizzled global layout (L2-hot,
// coalesced 1KB wave loads) -> no persistent qa file, no spill.
__global__ __launch_bounds__(256, 2)
void attn_kernel(const ushort_t* __restrict__ qsw, const ushort_t* __restrict__ kt,
                 const ushort_t* __restrict__ vb, ushort_t* __restrict__ pO,
                 float* __restrict__ lw)
{
    __shared__ ushort_t Sh[4 * 8192];   // [buf][K 64x128 | V 128x64], 64 KB

    const int blk = blockIdx.x;
    const int b   = blk & 7;            // batch == XCD (L2 locality)
    const int r   = blk >> 3;           // 0..63
    const int it  = r & 15;             // 16 i-tiles of 256
    const int sp  = r >> 4;             // j-quarter 0..3

    const int tid = threadIdx.x;
    const int w   = tid >> 6;
    const int l   = tid & 63;
    const int l31 = l & 31;
    const int g2  = l >> 5;

    const size_t boff = (size_t)b * NPOS * CH;
    const ushort_t* ktb = kt + boff;    // [n][c] * log2e
    const ushort_t* vbb = vb + boff;    // [c][n]

    const int i0  = it * 256;
    const int iw0 = i0 + w * 64;        // this wave's 64 i-rows
    const int j0b = sp * (NPOS / 4);    // 1024 j per block

    // per-lane pointer into swizzled Q; (ib,ck) frag = load at
    // qlane[qb(ib) + ck*512]  (512 ushorts = slots 2ck,2ck+1)
    const ushort_t* qlane = qsw + boff + (size_t)l * 8;
    const uint32 qb0 = (uint32)(((i0 >> 5) + 2 * w) * 16) << 8;
    const uint32 qb1 = qb0 + (16u << 8);

    auto stage = [&](int buf, int j0) {
        ushort_t* Kl = Sh + buf * 16384;
        ushort_t* Vl = Kl + 8192;
#pragma unroll
        for (int qq = 0; qq < 4; ++qq) {
            const int u = w * 256 + qq * 64 + l;
            {   // K: LDS linear (row=u>>4, slot=u&15); src pre-swizzled (row&7)
                const int row = u >> 4, sl = u & 15;
                gl_lds16(ktb + (size_t)(j0 + row) * CH + ((sl ^ (row & 7)) << 3),
                         Kl + (w * 256 + qq * 64) * 8);
            }
            {   // V: LDS linear (c=u>>3, slot=u&7); src pre-swizzled (c&7)
                const int c = u >> 3, sl = u & 7;
                gl_lds16(vbb + (size_t)c * NPOS + j0 + ((sl ^ (c & 7)) << 3),
                         Vl + (w * 256 + qq * 64) * 8);
            }
        }
    };

    stage(0, j0b);
    __syncthreads();   // buf0 staged

    f32x16 o[2][4];
#pragma unroll
    for (int ib = 0; ib < 2; ++ib)
#pragma unroll
        for (int cb = 0; cb < 4; ++cb) o[ib][cb] = z16();
    float lsum[2] = {0.f, 0.f};

    const int NT = (NPOS / 4) / 64;     // 16
    for (int t = 0; t < NT; ++t) {
        const int cur = t & 1;
        if (t + 1 < NT) stage(cur ^ 1, j0b + (t + 1) * 64);  // overlaps compute

        const ushort_t* Kl = Sh + cur * 16384;
        const ushort_t* Vl = Kl + 8192;

#pragma unroll
        for (int sub = 0; sub < 2; ++sub) {
            // ---- QK^T: S^T[32j x 32i] both i-blocks; K read once, Q from L2
            f32x16 s0 = z16(), s1 = z16();
            const int krow  = sub * 32 + l31;
            const int kbase = krow * 128;
            const int ksw   = krow & 7;
#pragma unroll 2
            for (int ck = 0; ck < 8; ++ck) {
                const bf16x8 q0 = *(const bf16x8*)&qlane[qb0 + ck * 512];
                const bf16x8 q1 = *(const bf16x8*)&qlane[qb1 + ck * 512];
                const bf16x8 ka =
                    *(const bf16x8*)&Kl[kbase + (((ck * 2 + g2) ^ ksw) << 3)];
                s0 = __builtin_amdgcn_mfma_f32_32x32x16_bf16(ka, q0, s0, 0, 0, 0);
                s1 = __builtin_amdgcn_mfma_f32_32x32x16_bf16(ka, q1, s1, 0, 0, 0);
            }

            // ---- exp2 (no max: scores bounded) + in-register bf16 pack
            uint32 d[2][4][2];
#pragma unroll
            for (int ib = 0; ib < 2; ++ib) {
                float p[16];
#pragma unroll
                for (int rg = 0; rg < 16; ++rg) {
                    p[rg] = EXP2(ib == 0 ? s0[rg] : s1[rg]);
                    lsum[ib] += p[rg];
                }
#pragma unroll
                for (int qd = 0; qd < 4; ++qd)
#pragma unroll
                    for (int td = 0; td < 2; ++td)
                        asm("v_cvt_pk_bf16_f32 %0, %1, %2"
                            : "=v"(d[ib][qd][td])
                            : "v"(p[4 * qd + 2 * td]), "v"(p[4 * qd + 2 * td + 1]));
            }

            // ---- PV: one V read feeds both i-blocks
#pragma unroll
            for (int kcl = 0; kcl < 2; ++kcl) {
                bf16x8 pf[2];
#pragma unroll
                for (int ib = 0; ib < 2; ++ib) {
                    uint32 a0 = d[ib][2 * kcl][0],     a1 = d[ib][2 * kcl][1];
                    uint32 b0 = d[ib][2 * kcl + 1][0], b1 = d[ib][2 * kcl + 1][1];
                    asm("v_permlane32_swap_b32 %0, %1" : "+v"(a0), "+v"(b0));
                    asm("v_permlane32_swap_b32 %0, %1" : "+v"(a1), "+v"(b1));
                    union { uint32 u[4]; bf16x8 v; } pu;
                    pu.u[0] = a0; pu.u[1] = a1; pu.u[2] = b0; pu.u[3] = b1;
                    pf[ib] = pu.v;
                }
                const int vsl = (sub * 2 + kcl) * 2 + g2;   // V j-slot
                __builtin_amdgcn_s_setprio(1);
#pragma unroll
                for (int cb = 0; cb < 4; ++cb) {
                    const int c = cb * 32 + l31;
                    const bf16x8 vv =
                        *(const bf16x8*)&Vl[c * 64 + ((vsl ^ (c & 7)) << 3)];
                    o[0][cb] = __builtin_amdgcn_mfma_f32_32x32x16_bf16(pf[0], vv, o[0][cb], 0, 0, 0);
                    o[1][cb] = __builtin_amdgcn_mfma_f32_32x32x16_bf16(pf[1], vv, o[1][cb], 0, 0, 0);
                }
                __builtin_amdgcn_s_setprio(0);
            }
        }
        __syncthreads();   // next buffer staged; this buffer free
    }

    // ---- epilogue: partial O (bf16) + partial l for this j-quarter
    float lp0 = lsum[0] + __shfl_xor(lsum[0], 32);
    float lp1 = lsum[1] + __shfl_xor(lsum[1], 32);
    ushort_t* pOb = pO + (size_t)sp * BCN + boff;
    float* lwb = lw + (size_t)sp * (BATCH * NPOS) + (size_t)b * NPOS;
#pragma unroll
    for (int rg = 0; rg < 16; ++rg) {
        const int rr = (rg & 3) + 8 * (rg >> 2) + 4 * g2;
#pragma unroll
        for (int ib = 0; ib < 2; ++ib) {
            const int n = iw0 + ib * 32 + rr;
            ushort_t* rowp = pOb + (size_t)n * CH;
            rowp[l31]      = f2bf(o[ib][0][rg]);
            rowp[32 + l31] = f2bf(o[ib][1][rg]);
            rowp[64 + l31] = f2bf(o[ib][2][rg]);
            rowp[96 + l31] = f2bf(o[ib][3][rg]);
        }
    }
    if (l < 32) {
        lwb[iw0 + l]      = lp0;
        lwb[iw0 + 32 + l] = lp1;
    }
}

// ------------------------------- k3: final proj via MFMA (merge fused, no LDS)
// grid 512 = 8 b x 64 n-tiles(64), 256 thr = 4 waves; wave w = co-block w.
// D[co][n] = mfma(Wf_frag, ao_frag); ao built in-register from 4 pO planes.
__global__ __launch_bounds__(256, 2)
void final_mfma_kernel(const ushort_t* __restrict__ pO, const float* __restrict__ lw,
                       const float* __restrict__ Wf, const float* __restrict__ bf_,
                       const float* __restrict__ x, float* __restrict__ out)
{
    const int blk = blockIdx.x;
    const int b   = blk & 7;
    const int n0  = (blk >> 3) * 64;

    const int tid = threadIdx.x;
    const int w   = tid >> 6;
    const int l   = tid & 63;
    const int l31 = l & 31;
    const int g2  = l >> 5;

    const int BN = BATCH * NPOS;
    const int co = w * 32 + l31;
    const size_t wrow = (size_t)co * CH;

    const int bn0 = b * NPOS + n0 + l31;
    const int bn1 = bn0 + 32;
    const float invl0 = 1.0f / (lw[bn0] + lw[BN + bn0] + lw[2 * BN + bn0] + lw[3 * BN + bn0]);
    const float invl1 = 1.0f / (lw[bn1] + lw[BN + bn1] + lw[2 * BN + bn1] + lw[3 * BN + bn1]);

    f32x16 a0 = z16(), a1 = z16();

#pragma unroll
    for (int k = 0; k < 8; ++k) {
        const int ko = k * 16 + g2 * 8;
        const bf16x8 wf = cvt8(Wf + wrow + ko, 1.0f);
        {
            const size_t base = (size_t)bn0 * CH + ko;
            const bf16x8 p0 = *(const bf16x8*)&pO[base];
            const bf16x8 p1 = *(const bf16x8*)&pO[base + (size_t)BCN];
            const bf16x8 p2 = *(const bf16x8*)&pO[base + (size_t)2 * BCN];
            const bf16x8 p3 = *(const bf16x8*)&pO[base + (size_t)3 * BCN];
            const bf16x8 aof = comb4(p0, p1, p2, p3, invl0);
            a0 = __builtin_amdgcn_mfma_f32_32x32x16_bf16(wf, aof, a0, 0, 0, 0);
        }
        {
            const size_t base = (size_t)bn1 * CH + ko;
            const bf16x8 p0 = *(const bf16x8*)&pO[base];
            const bf16x8 p1 = *(const bf16x8*)&pO[base + (size_t)BCN];
            const bf16x8 p2 = *(const bf16x8*)&pO[base + (size_t)2 * BCN];
            const bf16x8 p3 = *(const bf16x8*)&pO[base + (size_t)3 * BCN];
            const bf16x8 aof = comb4(p0, p1, p2, p3, invl1);
            a1 = __builtin_amdgcn_mfma_f32_32x32x16_bf16(wf, aof, a1, 0, 0, 0);
        }
    }

    // ---- epilogue: + bf + residual, fp32 contiguous stores
#pragma unroll
    for (int rg = 0; rg < 16; ++rg) {
        const int rr  = (rg & 3) + 8 * (rg >> 2) + 4 * g2;
        const int cov = w * 32 + rr;
        const float bfv = bf_[cov];
        const size_t rbase = (size_t)(b * CH + cov) * NPOS + n0;
        out[rbase + l31]      = a0[rg] + bfv + x[rbase + l31];
        out[rbase + 32 + l31] = a1[rg] + bfv + x[rbase + 32 + l31];
    }
}

// ---------------------------------------------------------------------------
extern "C" void kernel_launch(void* const* d_in, const int* in_sizes, int n_in,
                              void* d_out, int out_size, void* d_ws, size_t ws_size,
                              hipStream_t stream)
{
    (void)in_sizes; (void)n_in; (void)out_size;
    const float* x  = (const float*)d_in[0];
    const float* Wq = (const float*)d_in[1];
    const float* bq = (const float*)d_in[2];
    const float* Wk = (const float*)d_in[3];
    const float* bk = (const float*)d_in[4];
    const float* Wv = (const float*)d_in[5];
    const float* bv = (const float*)d_in[6];
    const float* Wf = (const float*)d_in[7];
    const float* bf = (const float*)d_in[8];
    float* out = (float*)d_out;

    const size_t MB = 1u << 20;
    const size_t need = 56 * MB + 512 * 1024;
    if (ws_size < need) {
        fprintf(stderr, "kernel_launch: ws_size %zu < needed %zu\n", ws_size, need);
        return;
    }
    char* wsc = (char*)d_ws;
    ushort_t* qt   = (ushort_t*)(wsc + 0);        //  8 MB bf16 swizzled
    ushort_t* kt   = (ushort_t*)(wsc + 8 * MB);   //  8 MB bf16 [b][n][c] *log2e
    ushort_t* vbuf = (ushort_t*)(wsc + 16 * MB);  //  8 MB bf16 [b][c][n]
    ushort_t* pO   = (ushort_t*)(wsc + 24 * MB);  // 32 MB bf16 [4][b][n][c]
    float*    lw   = (float*)(wsc + 56 * MB);     // 512 KB fp32 [4][b][n]

    qkv_mfma_kernel<<<dim3(512), 256, 0, stream>>>(
        x, Wq, bq, Wk, bk, Wv, bv, qt, kt, vbuf);
    attn_kernel<<<dim3(512), 256, 0, stream>>>(qt, kt, vbuf, pO, lw);
    final_mfma_kernel<<<dim3(512), 256, 0, stream>>>(
        pO, lw, Wf, bf, x, out);
}

// Round 14
// 111.239 us; speedup vs baseline: 1.1925x; 1.1925x over previous
//
#include <hip/hip_runtime.h>
#include <cstdio>

// ---------------------------------------------------------------------------
// TransformerLayer (B=8, C=128, N=4096) — round 14: revert to r12 (best,
// 111.3 us). r13's 64-i/L2-Q branch closed per pre-commitment (4th
// falsification of the family: structural 4-way LDS aliasing + L2 latency).
//   k1: fused qkv via MFMA (x hi+lo bf16 pair; W cvt per k-step; q/k in
//       [n][co] orientation, v in [co][n]).
//   k2: attention r9-exact (78 us): 512 blk x 4 waves, 64KB LDS dbuf,
//       global_load_lds, swapped QK^T, in-reg P, bf16 pO[2] partials.
//   k3: final proj via MFMA, zero LDS, merge fused (pO[0]+pO[1], normalize,
//       bias+residual epilogue).
// ws: qt 8 | kt 8 | v 8 | pO(bf16) 16 | lw 0.25 MB  (40.25 MB)
// ---------------------------------------------------------------------------

#define BATCH 8
#define CH    128
#define NPOS  4096
#define BCN   (BATCH * CH * NPOS)
#define LOG2E 1.4426950408889634f

typedef __attribute__((ext_vector_type(8)))  short bf16x8;
typedef __attribute__((ext_vector_type(16))) float f32x16;
typedef unsigned short ushort_t;
typedef unsigned int   uint32;

#if __has_builtin(__builtin_amdgcn_exp2f)
#define EXP2(x) __builtin_amdgcn_exp2f(x)
#else
#define EXP2(x) exp2f(x)
#endif

__device__ inline ushort_t f2bf(float f) {
    uint32 u = __float_as_uint(f);
    u += 0x7FFFu + ((u >> 16) & 1u);
    return (ushort_t)(u >> 16);
}
__device__ inline float bf2f(ushort_t h) {
    return __uint_as_float(((uint32)h) << 16);
}
__device__ inline f32x16 z16() {
    f32x16 r;
#pragma unroll
    for (int i = 0; i < 16; ++i) r[i] = 0.f;
    return r;
}
// async global->LDS, 16B/lane; LDS dst must be wave-uniform base
__device__ inline void gl_lds16(const ushort_t* g, ushort_t* l) {
    __builtin_amdgcn_global_load_lds(
        (const __attribute__((address_space(1))) uint32*)g,
        (__attribute__((address_space(3))) uint32*)l, 16, 0, 0);
}
// 8 fp32 -> bf16x8 (scaled), via v_cvt_pk_bf16_f32
__device__ inline bf16x8 cvt8(const float* p, float s) {
    const float4 a = *(const float4*)p;
    const float4 c = *(const float4*)(p + 4);
    uint32 u0, u1, u2, u3;
    asm("v_cvt_pk_bf16_f32 %0, %1, %2" : "=v"(u0) : "v"(a.x * s), "v"(a.y * s));
    asm("v_cvt_pk_bf16_f32 %0, %1, %2" : "=v"(u1) : "v"(a.z * s), "v"(a.w * s));
    asm("v_cvt_pk_bf16_f32 %0, %1, %2" : "=v"(u2) : "v"(c.x * s), "v"(c.y * s));
    asm("v_cvt_pk_bf16_f32 %0, %1, %2" : "=v"(u3) : "v"(c.z * s), "v"(c.w * s));
    union { uint32 u[4]; bf16x8 v; } r;
    r.u[0] = u0; r.u[1] = u1; r.u[2] = u2; r.u[3] = u3;
    return r.v;
}
// (p0+p1)*s elementwise -> bf16x8
__device__ inline bf16x8 comb8(bf16x8 p0, bf16x8 p1, float s) {
    uint32 u[4];
#pragma unroll
    for (int i = 0; i < 4; ++i) {
        const float a = (bf2f((ushort_t)p0[2 * i])     + bf2f((ushort_t)p1[2 * i]))     * s;
        const float b = (bf2f((ushort_t)p0[2 * i + 1]) + bf2f((ushort_t)p1[2 * i + 1])) * s;
        asm("v_cvt_pk_bf16_f32 %0, %1, %2" : "=v"(u[i]) : "v"(a), "v"(b));
    }
    union { uint32 uu[4]; bf16x8 v; } r;
    r.uu[0] = u[0]; r.uu[1] = u[1]; r.uu[2] = u[2]; r.uu[3] = u[3];
    return r.v;
}

// ------------------------------------------------- k1: fused qkv via MFMA
// grid 512 = 8 b x 64 n-tiles(64), 256 thr = 4 waves; wave w = co-block w.
// Phase 1: stage x[128c][64n] tile -> LDS hi/lo bf16 [n][c] (transposed).
// Phase 2: 8 k-steps: q/k: D[n][co] = mfma(x_frag, W_frag);
//                     v:   D[co][n] = mfma(W_frag, x_frag).
__global__ __launch_bounds__(256, 2)
void qkv_mfma_kernel(const float* __restrict__ x,
                     const float* __restrict__ Wq, const float* __restrict__ bq,
                     const float* __restrict__ Wk, const float* __restrict__ bk,
                     const float* __restrict__ Wv, const float* __restrict__ bv_,
                     ushort_t* __restrict__ qt, ushort_t* __restrict__ kt,
                     ushort_t* __restrict__ vb)
{
    __shared__ float    xs[32][69];      // staging chunk (8.8 KB)
    __shared__ ushort_t xh[64][136];     // x hi bf16 [n][c] (17.4 KB)
    __shared__ ushort_t xl[64][136];     // x lo bf16 [n][c] (17.4 KB)

    const int blk = blockIdx.x;
    const int b   = blk & 7;             // batch == XCD
    const int n0  = (blk >> 3) * 64;

    const int tid = threadIdx.x;
    const int w   = tid >> 6;
    const int l   = tid & 63;
    const int l31 = l & 31;
    const int g2  = l >> 5;

    // ---- phase 1: stage + transpose + hi/lo convert (block-cooperative)
    for (int c0 = 0; c0 < CH; c0 += 32) {
        __syncthreads();
        {
            const int r = tid >> 3, f4 = tid & 7;
            const size_t base = (size_t)(b * CH + c0 + r) * NPOS + n0;
            *(float4*)&xs[r][4 * f4]      = *(const float4*)&x[base + 4 * f4];
            *(float4*)&xs[r][32 + 4 * f4] = *(const float4*)&x[base + 32 + 4 * f4];
        }
        __syncthreads();
        {
            const int n = tid >> 2, oc = tid & 3;
            bf16x8 hi, lo;
#pragma unroll
            for (int m = 0; m < 8; ++m) {
                const float v = xs[oc * 8 + m][n];
                const ushort_t h = f2bf(v);
                hi[m] = (short)h;
                lo[m] = (short)f2bf(v - bf2f(h));
            }
            *(bf16x8*)&xh[n][c0 + oc * 8] = hi;
            *(bf16x8*)&xl[n][c0 + oc * 8] = lo;
        }
    }
    __syncthreads();

    // ---- phase 2: MFMA k-loop
    f32x16 aq0 = z16(), aq1 = z16(), ak0 = z16(), ak1 = z16();
    f32x16 av0 = z16(), av1 = z16();
    const int co = w * 32 + l31;
    const size_t wrow = (size_t)co * CH;

#pragma unroll
    for (int k = 0; k < 8; ++k) {
        const int ko = k * 16 + g2 * 8;
        const bf16x8 xh0 = *(const bf16x8*)&xh[l31][ko];
        const bf16x8 xh1 = *(const bf16x8*)&xh[32 + l31][ko];
        const bf16x8 xl0 = *(const bf16x8*)&xl[l31][ko];
        const bf16x8 xl1 = *(const bf16x8*)&xl[32 + l31][ko];
        const bf16x8 wqf = cvt8(Wq + wrow + ko, 1.0f);
        const bf16x8 wkf = cvt8(Wk + wrow + ko, LOG2E);
        const bf16x8 wvf = cvt8(Wv + wrow + ko, 1.0f);

        aq0 = __builtin_amdgcn_mfma_f32_32x32x16_bf16(xh0, wqf, aq0, 0, 0, 0);
        aq0 = __builtin_amdgcn_mfma_f32_32x32x16_bf16(xl0, wqf, aq0, 0, 0, 0);
        aq1 = __builtin_amdgcn_mfma_f32_32x32x16_bf16(xh1, wqf, aq1, 0, 0, 0);
        aq1 = __builtin_amdgcn_mfma_f32_32x32x16_bf16(xl1, wqf, aq1, 0, 0, 0);
        ak0 = __builtin_amdgcn_mfma_f32_32x32x16_bf16(xh0, wkf, ak0, 0, 0, 0);
        ak0 = __builtin_amdgcn_mfma_f32_32x32x16_bf16(xl0, wkf, ak0, 0, 0, 0);
        ak1 = __builtin_amdgcn_mfma_f32_32x32x16_bf16(xh1, wkf, ak1, 0, 0, 0);
        ak1 = __builtin_amdgcn_mfma_f32_32x32x16_bf16(xl1, wkf, ak1, 0, 0, 0);
        av0 = __builtin_amdgcn_mfma_f32_32x32x16_bf16(wvf, xh0, av0, 0, 0, 0);
        av0 = __builtin_amdgcn_mfma_f32_32x32x16_bf16(wvf, xl0, av0, 0, 0, 0);
        av1 = __builtin_amdgcn_mfma_f32_32x32x16_bf16(wvf, xh1, av1, 0, 0, 0);
        av1 = __builtin_amdgcn_mfma_f32_32x32x16_bf16(wvf, xl1, av1, 0, 0, 0);
    }

    // ---- epilogue
    const float bqv = bq[co];
    const float bkv = bk[co] * LOG2E;
    ushort_t* qtb = qt + (size_t)b * NPOS * CH;
    ushort_t* ktb = kt + (size_t)b * NPOS * CH;
    ushort_t* vbb = vb + (size_t)b * CH * NPOS;

#pragma unroll
    for (int rg = 0; rg < 16; ++rg) {
        const int rr = (rg & 3) + 8 * (rg >> 2) + 4 * g2;
        {   // q/k: D rows = n, cols = co -> contiguous 2B x 32-lane stores
            const int na = n0 + rr;
            const int nbr = n0 + 32 + rr;
            qtb[(size_t)na * CH + co]  = f2bf(aq0[rg] + bqv);
            qtb[(size_t)nbr * CH + co] = f2bf(aq1[rg] + bqv);
            ktb[(size_t)na * CH + co]  = f2bf(ak0[rg] + bkv);
            ktb[(size_t)nbr * CH + co] = f2bf(ak1[rg] + bkv);
        }
        {   // v: D rows = co, cols = n
            const int cov = w * 32 + rr;
            const float bvv = bv_[cov];
            vbb[(size_t)cov * NPOS + n0 + l31]      = f2bf(av0[rg] + bvv);
            vbb[(size_t)cov * NPOS + n0 + 32 + l31] = f2bf(av1[rg] + bvv);
        }
    }
}

// ------------------------------------------------------- k2: MFMA attention
// r9-exact (proven 78 us).
__global__ __launch_bounds__(256, 2)
void attn_kernel(const ushort_t* __restrict__ qt, const ushort_t* __restrict__ kt,
                 const ushort_t* __restrict__ vb, ushort_t* __restrict__ pO,
                 float* __restrict__ lw)
{
    __shared__ ushort_t Sh[4 * 8192];   // [buf][K 64x128 | V 128x64], 64 KB

    const int blk = blockIdx.x;
    const int b   = blk & 7;            // batch == XCD (L2 locality)
    const int r   = blk >> 3;           // 0..63
    const int it  = r & 31;
    const int sp  = r >> 5;             // j-split 0/1

    const int tid = threadIdx.x;
    const int w   = tid >> 6;
    const int l   = tid & 63;
    const int l31 = l & 31;
    const int g2  = l >> 5;

    const size_t boff = (size_t)b * NPOS * CH;
    const ushort_t* qtb = qt + boff;    // [n][c]
    const ushort_t* ktb = kt + boff;    // [n][c], pre-scaled by log2e
    const ushort_t* vbb = vb + boff;    // [c][n]

    const int i0  = it * 128;
    const int j0b = sp * (NPOS / 2);
    const int iw  = i0 + w * 32 + l31;  // this lane's Q row

    auto stage = [&](int buf, int j0) {
        ushort_t* Kl = Sh + buf * 16384;
        ushort_t* Vl = Kl + 8192;
#pragma unroll
        for (int qq = 0; qq < 4; ++qq) {
            const int u = w * 256 + qq * 64 + l;
            {   // K: LDS linear (row=u>>4, slot=u&15); src pre-swizzled
                const int row = u >> 4, sl = u & 15;
                gl_lds16(ktb + (size_t)(j0 + row) * CH + ((sl ^ (row & 7)) << 3),
                         Kl + (w * 256 + qq * 64) * 8);
            }
            {   // V: LDS linear (c=u>>3, slot=u&7); src pre-swizzled
                const int c = u >> 3, sl = u & 7;
                gl_lds16(vbb + (size_t)c * NPOS + j0 + ((sl ^ (c & 7)) << 3),
                         Vl + (w * 256 + qq * 64) * 8);
            }
        }
    };

    stage(0, j0b);

    bf16x8 qa[8];
#pragma unroll
    for (int ck = 0; ck < 8; ++ck)
        qa[ck] = *(const bf16x8*)&qtb[(size_t)iw * CH + (ck * 2 + g2) * 8];

    __syncthreads();   // buf0 staged

    f32x16 o0 = z16(), o1 = z16(), o2 = z16(), o3 = z16();
    float lsum = 0.f;

    const int NT = (NPOS / 2) / 64;     // 32
    for (int t = 0; t < NT; ++t) {
        const int cur = t & 1;
        if (t + 1 < NT) stage(cur ^ 1, j0b + (t + 1) * 64);  // overlaps compute

        const ushort_t* Kl = Sh + cur * 16384;
        const ushort_t* Vl = Kl + 8192;

#pragma unroll
        for (int sub = 0; sub < 2; ++sub) {
            f32x16 sS = z16();
            const int krow  = sub * 32 + l31;
            const int kbase = krow * 128;
            const int ksw   = krow & 7;
            __builtin_amdgcn_s_setprio(1);
#pragma unroll
            for (int ck = 0; ck < 8; ++ck) {
                const bf16x8 ka =
                    *(const bf16x8*)&Kl[kbase + (((ck * 2 + g2) ^ ksw) << 3)];
                sS = __builtin_amdgcn_mfma_f32_32x32x16_bf16(ka, qa[ck], sS, 0, 0, 0);
            }
            __builtin_amdgcn_s_setprio(0);

            float p[16];
#pragma unroll
            for (int rg = 0; rg < 16; ++rg) {
                p[rg] = EXP2(sS[rg]);
                lsum += p[rg];
            }
            uint32 d[4][2];
#pragma unroll
            for (int qd = 0; qd < 4; ++qd)
#pragma unroll
                for (int td = 0; td < 2; ++td)
                    asm("v_cvt_pk_bf16_f32 %0, %1, %2"
                        : "=v"(d[qd][td])
                        : "v"(p[4 * qd + 2 * td]), "v"(p[4 * qd + 2 * td + 1]));

#pragma unroll
            for (int kcl = 0; kcl < 2; ++kcl) {
                uint32 a0 = d[2 * kcl][0], a1 = d[2 * kcl][1];
                uint32 b0 = d[2 * kcl + 1][0], b1 = d[2 * kcl + 1][1];
                asm("v_permlane32_swap_b32 %0, %1" : "+v"(a0), "+v"(b0));
                asm("v_permlane32_swap_b32 %0, %1" : "+v"(a1), "+v"(b1));
                union { uint32 u[4]; bf16x8 v; } pf;
                pf.u[0] = a0; pf.u[1] = a1; pf.u[2] = b0; pf.u[3] = b1;

                const int vsl = (sub * 2 + kcl) * 2 + g2;   // V j-slot
                __builtin_amdgcn_s_setprio(1);
                {
                    const int c = l31;
                    const bf16x8 vv = *(const bf16x8*)&Vl[c * 64 + ((vsl ^ (c & 7)) << 3)];
                    o0 = __builtin_amdgcn_mfma_f32_32x32x16_bf16(pf.v, vv, o0, 0, 0, 0);
                }
                {
                    const int c = 32 + l31;
                    const bf16x8 vv = *(const bf16x8*)&Vl[c * 64 + ((vsl ^ (c & 7)) << 3)];
                    o1 = __builtin_amdgcn_mfma_f32_32x32x16_bf16(pf.v, vv, o1, 0, 0, 0);
                }
                {
                    const int c = 64 + l31;
                    const bf16x8 vv = *(const bf16x8*)&Vl[c * 64 + ((vsl ^ (c & 7)) << 3)];
                    o2 = __builtin_amdgcn_mfma_f32_32x32x16_bf16(pf.v, vv, o2, 0, 0, 0);
                }
                {
                    const int c = 96 + l31;
                    const bf16x8 vv = *(const bf16x8*)&Vl[c * 64 + ((vsl ^ (c & 7)) << 3)];
                    o3 = __builtin_amdgcn_mfma_f32_32x32x16_bf16(pf.v, vv, o3, 0, 0, 0);
                }
                __builtin_amdgcn_s_setprio(0);
            }
        }
        __syncthreads();   // next buffer staged; this buffer free
    }

    // ---- epilogue: partial O (bf16) + partial l
    const float lpart = lsum + __shfl_xor(lsum, 32);
    ushort_t* pOb = pO + (size_t)sp * BCN + boff;
    float* lwb = lw + (size_t)sp * (BATCH * NPOS) + (size_t)b * NPOS;
#pragma unroll
    for (int rg = 0; rg < 16; ++rg) {
        const int rr = (rg & 3) + 8 * (rg >> 2) + 4 * g2;
        const int n  = i0 + w * 32 + rr;
        ushort_t* rowp = pOb + (size_t)n * CH;
        rowp[l31]      = f2bf(o0[rg]);
        rowp[32 + l31] = f2bf(o1[rg]);
        rowp[64 + l31] = f2bf(o2[rg]);
        rowp[96 + l31] = f2bf(o3[rg]);
    }
    if (l < 32) lwb[i0 + w * 32 + l] = lpart;
}

// ------------------------------- k3: final proj via MFMA (merge fused, no LDS)
// grid 512 = 8 b x 64 n-tiles(64), 256 thr = 4 waves; wave w = co-block w.
// D[co][n] = mfma(Wf_frag, ao_frag); ao built in-register from pO[0]+pO[1].
__global__ __launch_bounds__(256, 2)
void final_mfma_kernel(const ushort_t* __restrict__ pO, const float* __restrict__ lw,
                       const float* __restrict__ Wf, const float* __restrict__ bf_,
                       const float* __restrict__ x, float* __restrict__ out)
{
    const int blk = blockIdx.x;
    const int b   = blk & 7;
    const int n0  = (blk >> 3) * 64;

    const int tid = threadIdx.x;
    const int w   = tid >> 6;
    const int l   = tid & 63;
    const int l31 = l & 31;
    const int g2  = l >> 5;

    const int BN = BATCH * NPOS;
    const int co = w * 32 + l31;
    const size_t wrow = (size_t)co * CH;

    const int bn0 = b * NPOS + n0 + l31;
    const int bn1 = bn0 + 32;
    const float invl0 = 1.0f / (lw[bn0] + lw[BN + bn0]);
    const float invl1 = 1.0f / (lw[bn1] + lw[BN + bn1]);

    f32x16 a0 = z16(), a1 = z16();

#pragma unroll
    for (int k = 0; k < 8; ++k) {
        const int ko = k * 16 + g2 * 8;
        const bf16x8 wf = cvt8(Wf + wrow + ko, 1.0f);
        {
            const size_t base = (size_t)bn0 * CH + ko;
            const bf16x8 p0 = *(const bf16x8*)&pO[base];
            const bf16x8 p1 = *(const bf16x8*)&pO[base + (size_t)BCN];
            const bf16x8 aof = comb8(p0, p1, invl0);
            a0 = __builtin_amdgcn_mfma_f32_32x32x16_bf16(wf, aof, a0, 0, 0, 0);
        }
        {
            const size_t base = (size_t)bn1 * CH + ko;
            const bf16x8 p0 = *(const bf16x8*)&pO[base];
            const bf16x8 p1 = *(const bf16x8*)&pO[base + (size_t)BCN];
            const bf16x8 aof = comb8(p0, p1, invl1);
            a1 = __builtin_amdgcn_mfma_f32_32x32x16_bf16(wf, aof, a1, 0, 0, 0);
        }
    }

    // ---- epilogue: + bf + residual, fp32 contiguous stores
#pragma unroll
    for (int rg = 0; rg < 16; ++rg) {
        const int rr  = (rg & 3) + 8 * (rg >> 2) + 4 * g2;
        const int cov = w * 32 + rr;
        const float bfv = bf_[cov];
        const size_t rbase = (size_t)(b * CH + cov) * NPOS + n0;
        out[rbase + l31]      = a0[rg] + bfv + x[rbase + l31];
        out[rbase + 32 + l31] = a1[rg] + bfv + x[rbase + 32 + l31];
    }
}

// ---------------------------------------------------------------------------
extern "C" void kernel_launch(void* const* d_in, const int* in_sizes, int n_in,
                              void* d_out, int out_size, void* d_ws, size_t ws_size,
                              hipStream_t stream)
{
    (void)in_sizes; (void)n_in; (void)out_size;
    const float* x  = (const float*)d_in[0];
    const float* Wq = (const float*)d_in[1];
    const float* bq = (const float*)d_in[2];
    const float* Wk = (const float*)d_in[3];
    const float* bk = (const float*)d_in[4];
    const float* Wv = (const float*)d_in[5];
    const float* bv = (const float*)d_in[6];
    const float* Wf = (const float*)d_in[7];
    const float* bf = (const float*)d_in[8];
    float* out = (float*)d_out;

    const size_t MB = 1u << 20;
    const size_t need = 40 * MB + 256 * 1024;
    if (ws_size < need) {
        fprintf(stderr, "kernel_launch: ws_size %zu < needed %zu\n", ws_size, need);
        return;
    }
    char* wsc = (char*)d_ws;
    ushort_t* qt   = (ushort_t*)(wsc + 0);        //  8 MB bf16 [b][n][c]
    ushort_t* kt   = (ushort_t*)(wsc + 8 * MB);   //  8 MB bf16 [b][n][c] *log2e
    ushort_t* vbuf = (ushort_t*)(wsc + 16 * MB);  //  8 MB bf16 [b][c][n]
    ushort_t* pO   = (ushort_t*)(wsc + 24 * MB);  // 16 MB bf16 [2][b][n][c]
    float*    lw   = (float*)(wsc + 40 * MB);     // 256 KB fp32 [2][b][n]

    qkv_mfma_kernel<<<dim3(512), 256, 0, stream>>>(
        x, Wq, bq, Wk, bk, Wv, bv, qt, kt, vbuf);
    attn_kernel<<<dim3(512), 256, 0, stream>>>(qt, kt, vbuf, pO, lw);
    final_mfma_kernel<<<dim3(512), 256, 0, stream>>>(
        pO, lw, Wf, bf, x, out);
}